// Round 15
// baseline (692.018 us; speedup 1.0000x reference)
//
#include <hip/hip_runtime.h>
#include <hip/hip_bf16.h>

#define M 65536
#define N 3000
#define NPAD 3072
#define K 768
#define NT_K 24      // 768/32 K-slabs (BK=32)
#define NTIL 24      // 3072 / 128 n-tiles
#define KSP 128
#define MAXL 8192
#define GAPTHR 4.5e-3f
#define MAXAMB 16384
#define MAXWL 196608
#define NEGINF -3.4e38f

typedef __attribute__((ext_vector_type(8))) _Float16 f16x8;
typedef __attribute__((ext_vector_type(4))) float f32x4;
typedef unsigned long long u64;
typedef unsigned int u32;

#define AS1 __attribute__((address_space(1)))
#define AS3 __attribute__((address_space(3)))

// ws layout (bytes)
#define OFF_A2   0ull            // M*768*2   = 100663296
#define OFF_B2   100663296ull    // 3072*768*2 = 4718592
#define OFF_GTOP 105381888ull    // M*24*2*8  = 25165824
#define OFF_RB   130547712ull    // M*8       = 524288
#define OFF_R    131072000ull    // M*4       = 262144
#define OFF_AMB  131334144ull    // 16384*4
#define OFF_WL   131465216ull    // 196608*4  = 786432
#define OFF_CNT  132251648ull    // 2 u32 (+pad)
#define OFF_CM   132251904ull    // 3072*8 = 24576 chunk bitmaps
#define WS_NEED  132276480ull

__device__ inline unsigned short f2h(float x) {
  _Float16 h = (_Float16)x;
  return *reinterpret_cast<unsigned short*>(&h);
}
__device__ inline u32 fkey(float v) {
  u32 ub = __float_as_uint(v);
  return (ub & 0x80000000u) ? ~ub : (ub | 0x80000000u);
}
__device__ inline float keyf(u32 key) {
  u32 ub = (key & 0x80000000u) ? (key ^ 0x80000000u) : ~key;
  return __uint_as_float(ub);
}
__device__ inline void gload16(const void* g, void* l) {
  __builtin_amdgcn_global_load_lds((AS1 u32*)g, (AS3 u32*)l, 16, 0, 0);
}

// ---------------- K0a: X -> fp16 ----------------
__global__ __launch_bounds__(256) void k_convx(const float* __restrict__ X,
                                               unsigned short* __restrict__ A2) {
  const int tot = M * (K / 8);
  for (int i = blockIdx.x * 256 + threadIdx.x; i < tot; i += gridDim.x * 256) {
    size_t base = (size_t)i * 8;
    float4 v0 = *reinterpret_cast<const float4*>(X + base);
    float4 v1 = *reinterpret_cast<const float4*>(X + base + 4);
    ushort4 h0, h1;
    h0.x = f2h(v0.x); h0.y = f2h(v0.y); h0.z = f2h(v0.z); h0.w = f2h(v0.w);
    h1.x = f2h(v1.x); h1.y = f2h(v1.y); h1.z = f2h(v1.z); h1.w = f2h(v1.w);
    *reinterpret_cast<ushort4*>(A2 + base) = h0;
    *reinterpret_cast<ushort4*>(A2 + base + 4) = h1;
  }
}

// ---------------- K0b: MU -> fp16, pad rows zero; reset counters/maps -------
__global__ __launch_bounds__(256) void k_convmu(const float* __restrict__ MU,
                                                unsigned short* __restrict__ B2,
                                                u32* __restrict__ cnts,
                                                u64* __restrict__ chunkmap,
                                                float* __restrict__ dis_slot) {
  int j = blockIdx.x, t = threadIdx.x;
  if (j == 0 && t == 0) { cnts[0] = 0u; cnts[1] = 0u; }
  if (j == 0 && t == 1) *dis_slot = 0.0f;
  if (t == 2 && j < N) chunkmap[j] = 0ull;
  for (int c = t; c < K; c += 256) {
    float x = (j < N) ? MU[(size_t)j * K + c] : 0.0f;
    B2[(size_t)j * K + c] = f2h(x);
  }
}

// ---------------- K1: 128x128 4-wave, BK=32, 3-buf 48KiB, 1 barrier/slab ----
// Change vs R14: triple-buffered LDS; STAGE(kt+2) issued at slab TOP (target
// buffer (kt+2)%3 is read by nobody) -> prefetch distance 2 slabs > HBM/L2
// latency; ONE barrier per slab (stage of buf q is ordered after all reads of
// q by the single barrier; per-wave lgkmcnt(0) drains own reads first).
// Swizzle/read/write maps identical to R10-R14 (0 conflicts verified).
// [R11/R12 lesson: no launch_bounds min-waves — spill hazard.]
__global__ __launch_bounds__(256) void k_gemm(const unsigned short* __restrict__ A2,
                                              const unsigned short* __restrict__ B2,
                                              u64* __restrict__ gtop) {
  __shared__ unsigned short smem[24576];  // 48 KiB: A[3][4096], B[3][4096]

  const int bid = blockIdx.x;
  const int xcd = bid & 7, idx = bid >> 3;
  const int g = idx / 96, rem = idx % 96;
  const int nt = rem >> 2, mi = rem & 3;
  const int mt = xcd * 64 + g * 4 + mi;
  const int m0 = mt * 128, n0 = nt * 128;

  const int t = threadIdx.x;
  const int w = t >> 6, ln = t & 63;
  const int wr = w >> 1, wc = w & 1;          // 2M x 2N waves
  const int li = ln & 15, lg = ln >> 4;

  const int r0 = t >> 2;
  const int c0 = ((t & 3) ^ ((t >> 3) & 3)) * 8;
  const unsigned short* pa0 = A2 + (size_t)(m0 + r0) * K + c0;
  const unsigned short* pb0 = B2 + (size_t)(n0 + r0) * K + c0;

  f32x4 acc[4][4] = {};

  const int rA = wr * 64 + li;
  const int rB = wc * 64 + li;
  const int cc = (lg ^ ((li >> 1) & 3)) * 8;  // read-side swizzled chunk

#define STAGE(kt_, p_)                                                        \
  {                                                                           \
    int k0_ = (kt_) * 32;                                                     \
    gload16(pa0 + k0_, smem + (p_) * 4096 + t * 8);                           \
    gload16(pa0 + (size_t)64 * K + k0_, smem + (p_) * 4096 + 2048 + t * 8);   \
    gload16(pb0 + k0_, smem + 12288 + (p_) * 4096 + t * 8);                   \
    gload16(pb0 + (size_t)64 * K + k0_,                                       \
            smem + 12288 + (p_) * 4096 + 2048 + t * 8);                       \
  }

  STAGE(0, 0);
  STAGE(1, 1);

  int p = 0;
  for (int kt = 0; kt < NT_K; ++kt) {
    if (kt == NT_K - 1)
      asm volatile("s_waitcnt vmcnt(0)" ::: "memory");
    else
      asm volatile("s_waitcnt vmcnt(4)" ::: "memory");  // secures slab kt
    __builtin_amdgcn_s_barrier();
    asm volatile("" ::: "memory");

    // prefetch slab kt+2 into buffer (kt+2)%3 (read by nobody this slab)
    if (kt < NT_K - 2) {
      int p2 = p + 2; if (p2 >= 3) p2 -= 3;
      STAGE(kt + 2, p2);
    }

    const unsigned short* baseA = smem + p * 4096;
    const unsigned short* baseB = smem + 12288 + p * 4096;
    f16x8 aa[4], bb[4];
#pragma unroll
    for (int n_ = 0; n_ < 4; ++n_)
      bb[n_] = *reinterpret_cast<const f16x8*>(baseB + (rB + n_ * 16) * 32 + cc);
#pragma unroll
    for (int m_ = 0; m_ < 4; ++m_)
      aa[m_] = *reinterpret_cast<const f16x8*>(baseA + (rA + m_ * 16) * 32 + cc);

    __builtin_amdgcn_s_setprio(1);
#pragma unroll
    for (int m_ = 0; m_ < 4; ++m_)
#pragma unroll
      for (int n_ = 0; n_ < 4; ++n_)
        acc[m_][n_] = __builtin_amdgcn_mfma_f32_16x16x32_f16(
            aa[m_], bb[n_], acc[m_][n_], 0, 0, 0);
    __builtin_amdgcn_s_setprio(0);

    // drain this wave's LDS reads before the next slab's barrier (cheap: all
    // reads already consumed by the MFMAs above).
    asm volatile("s_waitcnt lgkmcnt(0)" ::: "memory");

    p += 1; if (p >= 3) p -= 3;
  }

  // ---- epilogue: per-row top2 via f32 butterflies ----
  u64* stop = reinterpret_cast<u64*>(smem);  // 4KB, overlays buf0 (A region)
#pragma unroll
  for (int m = 0; m < 4; ++m)
#pragma unroll
    for (int reg = 0; reg < 4; ++reg) {
      float l1 = NEGINF, l2 = NEGINF;
      int nb = 0;
#pragma unroll
      for (int n = 0; n < 4; ++n) {
        int col = n0 + wc * 64 + n * 16 + li;
        float v = (col < N) ? acc[m][n][reg] : NEGINF;
        if (v > l1) { l2 = l1; l1 = v; nb = n; }
        else if (v > l2) l2 = v;
      }
      const float loc1 = l1;
#pragma unroll
      for (int s = 1; s < 16; s <<= 1) {
        float o1 = __shfl_xor(l1, s, 64);
        float o2 = __shfl_xor(l2, s, 64);
        float hi = fmaxf(l1, o1);
        float lo = fminf(l1, o1);
        l2 = fmaxf(lo, fmaxf(l2, o2));
        l1 = hi;
      }
      unsigned long long bal = __ballot(loc1 == l1);
      unsigned mask16 = (unsigned)(bal >> (lg * 16)) & 0xffffu;
      int first = __builtin_ctz(mask16 | 0x10000u);
      int nbo = __shfl(nb, lg * 16 + first, 64);
      int col1 = n0 + wc * 64 + nbo * 16 + first;
      if (li == 0) {
        int rloc = wr * 64 + m * 16 + lg * 4 + reg;
        stop[(wc * 128 + rloc) * 2 + 0] =
            ((u64)fkey(l1) << 32) | (u32)(~(u32)col1);
        stop[(wc * 128 + rloc) * 2 + 1] = ((u64)fkey(l2) << 32);
      }
    }
  __syncthreads();
  if (t < 128) {
    u64 g1 = 0, g2 = 0;
#pragma unroll
    for (int q = 0; q < 2; ++q) {
      u64 a1 = stop[(q * 128 + t) * 2 + 0], a2 = stop[(q * 128 + t) * 2 + 1];
      u64 n1 = g1 > a1 ? g1 : a1;
      u64 lo = g1 > a1 ? a1 : g1;
      u64 mx = g2 > a2 ? g2 : a2;
      g2 = lo > mx ? lo : mx;
      g1 = n1;
    }
    u64* dst = gtop + ((size_t)(m0 + t) * NTIL + nt) * 2;
    dst[0] = g1;
    dst[1] = g2;
  }
}

// ---------------- K2: merge 24 tiles -> r, worklist + chunk bitmap ----------
__global__ __launch_bounds__(256) void k_reduce(const u64* __restrict__ gtop,
                                                int* __restrict__ r,
                                                int* __restrict__ amb,
                                                u64* __restrict__ rbest,
                                                u32* __restrict__ wl,
                                                u32* __restrict__ cnts,
                                                u64* __restrict__ chunkmap) {
  int row = blockIdx.x * 256 + threadIdx.x;
  if (row >= M) return;
  const u64* src = gtop + (size_t)row * NTIL * 2;
  u64 tops[NTIL];
  u64 g1 = 0, g2 = 0;
#pragma unroll
  for (int tt = 0; tt < NTIL; ++tt) {
    u64 a1 = src[tt * 2], a2 = src[tt * 2 + 1];
    tops[tt] = a1;
    u64 n1 = g1 > a1 ? g1 : a1;
    u64 lo = g1 > a1 ? a1 : g1;
    u64 mx = g2 > a2 ? g2 : a2;
    g2 = lo > mx ? lo : mx;
    g1 = n1;
  }
  int jbest = (int)(~(u32)(g1 & 0xffffffffull));
  r[row] = jbest;
  atomicOr(&chunkmap[jbest], 1ull << (row >> 10));
  float v1 = keyf((u32)(g1 >> 32)), v2 = keyf((u32)(g2 >> 32));
  if (v1 - v2 < GAPTHR) {
    u32 idx = atomicAdd(&cnts[0], 1u);
    if (idx < MAXAMB) {
      amb[idx] = row;
      rbest[row] = 0ull;
      float thr = v1 - GAPTHR;
#pragma unroll
      for (int tt = 0; tt < NTIL; ++tt) {
        if (keyf((u32)(tops[tt] >> 32)) >= thr) {
          u32 wi = atomicAdd(&cnts[1], 1u);
          if (wi < MAXWL) wl[wi] = ((u32)row << 5) | (u32)tt;
        }
      }
    }
  }
}

// ---------------- K3: exact fp32 re-argmax over compact worklist ------------
__global__ __launch_bounds__(256) void k_refine(const float* __restrict__ X,
                                                const float* __restrict__ MU,
                                                const u32* __restrict__ wl,
                                                const u32* __restrict__ cnts,
                                                u64* __restrict__ rbest) {
  __shared__ float xrow[768];
  __shared__ u64 wb[4];
  const int t = threadIdx.x, w = t >> 6, ln = t & 63;
  const int nw = (int)min(cnts[1], (u32)MAXWL);
  for (int u = blockIdx.x; u < nw; u += gridDim.x) {
    const u32 e = wl[u];
    const int row = (int)(e >> 5), tile = (int)(e & 31);

    xrow[t] = X[(size_t)row * K + t];
    xrow[t + 256] = X[(size_t)row * K + t + 256];
    xrow[t + 512] = X[(size_t)row * K + t + 512];
    __syncthreads();

    u64 best = 0;
    for (int q = 0; q < 8; ++q) {
      const int cbase = tile * 128 + w * 32 + q * 4;
      const float* m0p = MU + (size_t)min(cbase + 0, N - 1) * K;
      const float* m1p = MU + (size_t)min(cbase + 1, N - 1) * K;
      const float* m2p = MU + (size_t)min(cbase + 2, N - 1) * K;
      const float* m3p = MU + (size_t)min(cbase + 3, N - 1) * K;
      float p0 = 0.f, p1 = 0.f, p2 = 0.f, p3 = 0.f;
#pragma unroll
      for (int it = 0; it < 3; ++it) {
        int d4 = (ln + it * 64) * 4;
        float4 xv = *reinterpret_cast<const float4*>(&xrow[d4]);
        float4 a0 = *reinterpret_cast<const float4*>(m0p + d4);
        float4 a1 = *reinterpret_cast<const float4*>(m1p + d4);
        float4 a2 = *reinterpret_cast<const float4*>(m2p + d4);
        float4 a3 = *reinterpret_cast<const float4*>(m3p + d4);
        p0 += xv.x * a0.x + xv.y * a0.y + xv.z * a0.z + xv.w * a0.w;
        p1 += xv.x * a1.x + xv.y * a1.y + xv.z * a1.z + xv.w * a1.w;
        p2 += xv.x * a2.x + xv.y * a2.y + xv.z * a2.z + xv.w * a2.w;
        p3 += xv.x * a3.x + xv.y * a3.y + xv.z * a3.z + xv.w * a3.w;
      }
#pragma unroll
      for (int s = 32; s; s >>= 1) {
        p0 += __shfl_xor(p0, s, 64);
        p1 += __shfl_xor(p1, s, 64);
        p2 += __shfl_xor(p2, s, 64);
        p3 += __shfl_xor(p3, s, 64);
      }
      if (ln == 0) {
        float ps[4] = {p0, p1, p2, p3};
#pragma unroll
        for (int i = 0; i < 4; ++i) {
          int c = cbase + i;
          if (c < N) {
            u64 pk = ((u64)fkey(ps[i]) << 32) | (u32)(~(u32)c);
            if (pk > best) best = pk;
          }
        }
      }
    }
    if (ln == 0) wb[w] = best;
    __syncthreads();
    if (t == 0) {
      u64 b = wb[0];
#pragma unroll
      for (int i = 1; i < 4; ++i)
        if (wb[i] > b) b = wb[i];
      atomicMax(&rbest[row], b);
    }
    __syncthreads();
  }
}

// ---------------- K3b: decode refined assignments (+bitmap update) ----------
__global__ __launch_bounds__(256) void k_decode2(const int* __restrict__ amb,
                                                 const u64* __restrict__ rbest,
                                                 const u32* __restrict__ cnts,
                                                 int* __restrict__ r,
                                                 u64* __restrict__ chunkmap) {
  int i = blockIdx.x * 256 + threadIdx.x;
  int n_amb = (int)min(cnts[0], (u32)MAXAMB);
  if (i < n_amb) {
    int row = amb[i];
    int jn = (int)(~(u32)(rbest[row] & 0xffffffffull));
    r[row] = jn;
    atomicOr(&chunkmap[jn], 1ull << (row >> 10));
  }
}

// ---------------- K4: finalize (chunk-bitmap skip + ILP member sum) ---------
__global__ __launch_bounds__(256) void k_finalize(const float* __restrict__ X,
                                                  const float* __restrict__ MU,
                                                  const int* __restrict__ r,
                                                  const u64* __restrict__ chunkmap,
                                                  float* __restrict__ out,
                                                  float* __restrict__ dis_slot) {
#pragma clang fp contract(off)
  const int j = blockIdx.x;
  const int t = threadIdx.x;
  const int lane = t & 63;
  const int wid = t >> 6;
  __shared__ int list[MAXL];
  __shared__ int wc4[4][4];   // [wave][group]
  __shared__ float red[4];
  __shared__ unsigned hist[256];
  __shared__ int selI;

  const u64 cmap = chunkmap[j];
  int cnt = 0;
  for (int ch = 0; ch < 64; ++ch) {
    if (!((cmap >> ch) & 1ull)) continue;  // block-uniform skip
    const int base = ch << 10;
    bool f[4];
    u64 bm[4];
#pragma unroll
    for (int q = 0; q < 4; ++q) {
      f[q] = (r[base + q * 256 + t] == j);
      bm[q] = __ballot(f[q]);
    }
    if (lane == 0) {
#pragma unroll
      for (int q = 0; q < 4; ++q) wc4[wid][q] = __popcll(bm[q]);
    }
    __syncthreads();
    int goff = cnt;
#pragma unroll
    for (int q = 0; q < 4; ++q) {
      if (f[q]) {
        int off = goff;
        for (int ww = 0; ww < wid; ++ww) off += wc4[ww][q];
        int pos = off + __popcll(bm[q] & ((1ull << lane) - 1ull));
        if (pos < MAXL) list[pos] = base + q * 256 + t;
      }
      goff += wc4[0][q] + wc4[1][q] + wc4[2][q] + wc4[3][q];
    }
    cnt = goff;
    __syncthreads();
  }
  int cl = cnt < MAXL ? cnt : MAXL;

  // member sums: 4 independent accumulator chains (ILP), fixed-order combine
  float a0 = 0.f, a1 = 0.f, a2 = 0.f, a3 = 0.f;
  float b0 = 0.f, b1 = 0.f, b2 = 0.f, b3 = 0.f;
  float c0 = 0.f, c1 = 0.f, c2 = 0.f, c3 = 0.f;
  int m = 0;
  for (; m + 3 < cl; m += 4) {
    const float* x0 = X + (size_t)list[m + 0] * K;
    const float* x1 = X + (size_t)list[m + 1] * K;
    const float* x2 = X + (size_t)list[m + 2] * K;
    const float* x3 = X + (size_t)list[m + 3] * K;
    a0 += x0[t]; b0 += x0[t + 256]; c0 += x0[t + 512];
    a1 += x1[t]; b1 += x1[t + 256]; c1 += x1[t + 512];
    a2 += x2[t]; b2 += x2[t + 256]; c2 += x2[t + 512];
    a3 += x3[t]; b3 += x3[t + 256]; c3 += x3[t + 512];
  }
  for (; m < cl; ++m) {
    const float* xr = X + (size_t)list[m] * K;
    a0 += xr[t]; b0 += xr[t + 256]; c0 += xr[t + 512];
  }
  float s0 = ((a0 + a1) + a2) + a3;
  float s1 = ((b0 + b1) + b2) + b3;
  float s2 = ((c0 + c1) + c2) + c3;

  const float mu0 = MU[(size_t)j * K + t];
  const float mu1 = MU[(size_t)j * K + t + 256];
  const float mu2 = MU[(size_t)j * K + t + 512];

  float u0, u1, u2;
  if (cnt >= 1) {
    float c = (float)cnt;
    u0 = s0 / c; u1 = s1 / c; u2 = s2 / c;
  } else {
    u0 = mu0; u1 = mu1; u2 = mu2;
  }
  float v0 = u0 * 0.2f + mu0 * 0.8f;
  float v1 = u1 * 0.2f + mu1 * 0.8f;
  float v2 = u2 * 0.2f + mu2 * 0.8f;

  float ss = v0 * v0 + v1 * v1 + v2 * v2;
#pragma unroll
  for (int s = 32; s > 0; s >>= 1) ss += __shfl_down(ss, s, 64);
  if (lane == 0) red[wid] = ss;
  __syncthreads();
  float tot = red[0] + red[1] + red[2] + red[3];
  float den = sqrtf(tot);
  den = fmaxf(den, 1e-12f);
  float un0 = v0 / den, un1 = v1 / den, un2 = v2 / den;
  unsigned k0b = __float_as_uint(fabsf(un0));
  unsigned k1b = __float_as_uint(fabsf(un1));
  unsigned k2b = __float_as_uint(fabsf(un2));
  __syncthreads();

  unsigned cur = 0;
  int need = KSP;
  for (int sh = 24; sh >= 0; sh -= 8) {
    hist[t] = 0u;
    if (t == 0) selI = -1;
    __syncthreads();
    bool m0_ = (sh == 24) || ((k0b >> (sh + 8)) == (cur >> (sh + 8)));
    bool m1_ = (sh == 24) || ((k1b >> (sh + 8)) == (cur >> (sh + 8)));
    bool m2_ = (sh == 24) || ((k2b >> (sh + 8)) == (cur >> (sh + 8)));
    if (m0_) atomicAdd(&hist[(k0b >> sh) & 255u], 1u);
    if (m1_) atomicAdd(&hist[(k1b >> sh) & 255u], 1u);
    if (m2_) atomicAdd(&hist[(k2b >> sh) & 255u], 1u);
    __syncthreads();
#pragma unroll
    for (int off = 1; off < 256; off <<= 1) {
      unsigned nb = (t + off < 256) ? hist[t + off] : 0u;
      __syncthreads();
      hist[t] += nb;
      __syncthreads();
    }
    if (hist[t] >= (unsigned)need) atomicMax(&selI, t);
    __syncthreads();
    int b = selI < 0 ? 0 : selI;
    unsigned above = (b < 255) ? hist[b + 1] : 0u;
    cur |= ((unsigned)b << sh);
    need = need - (int)above;
    __syncthreads();
  }
  unsigned th = cur;

  float o0 = (k0b >= th) ? un0 : 0.0f;
  float o1 = (k1b >= th) ? un1 : 0.0f;
  float o2 = (k2b >= th) ? un2 : 0.0f;
  out[(size_t)j * K + t] = o0;
  out[(size_t)j * K + t + 256] = o1;
  out[(size_t)j * K + t + 512] = o2;

  float q0 = o0 - mu0, q1 = o1 - mu1, q2 = o2 - mu2;
  float dq = q0 * q0 + q1 * q1 + q2 * q2;
#pragma unroll
  for (int s = 32; s > 0; s >>= 1) dq += __shfl_down(dq, s, 64);
  __syncthreads();
  if (lane == 0) red[wid] = dq;
  __syncthreads();
  if (t == 0) {
    float dtot = red[0] + red[1] + red[2] + red[3];
    float dn = sqrtf(dtot);
    atomicMax((unsigned*)dis_slot, __float_as_uint(dn));
  }
}

// ================= fallback fp32 path (ws too small) =================
__global__ __launch_bounds__(256) void k0_init(u64* __restrict__ best,
                                               float* __restrict__ dis_slot) {
  int i = blockIdx.x * 256 + threadIdx.x;
  if (i < M) best[i] = 0ull;
  if (i == 0) *dis_slot = 0.0f;
}

__global__ __launch_bounds__(256) void k1_f32(const float* __restrict__ X,
                                              const float* __restrict__ MU,
                                              u64* __restrict__ best) {
  __shared__ float Asf[16][64];
  __shared__ float Bsf[16][64];
  const int m0 = blockIdx.x * 64;
  const int n0 = blockIdx.y * 64;
  const int t = threadIdx.x;
  const int tx = t & 15, ty = t >> 4;
  const int lrow = t >> 2, lcg = t & 3;

  float acc[4][4];
#pragma unroll
  for (int i = 0; i < 4; ++i)
#pragma unroll
    for (int jj = 0; jj < 4; ++jj) acc[i][jj] = 0.0f;

  const float* aptr = X + (size_t)(m0 + lrow) * K + lcg * 4;
  const bool bvalid = (n0 + lrow) < N;
  const float* bptr = MU + (size_t)(bvalid ? (n0 + lrow) : 0) * K + lcg * 4;

  for (int k0 = 0; k0 < K; k0 += 16) {
    float4 av = *reinterpret_cast<const float4*>(aptr + k0);
    float4 bv = make_float4(0.f, 0.f, 0.f, 0.f);
    if (bvalid) bv = *reinterpret_cast<const float4*>(bptr + k0);
    Asf[lcg * 4 + 0][lrow] = av.x; Asf[lcg * 4 + 1][lrow] = av.y;
    Asf[lcg * 4 + 2][lrow] = av.z; Asf[lcg * 4 + 3][lrow] = av.w;
    Bsf[lcg * 4 + 0][lrow] = bv.x; Bsf[lcg * 4 + 1][lrow] = bv.y;
    Bsf[lcg * 4 + 2][lrow] = bv.z; Bsf[lcg * 4 + 3][lrow] = bv.w;
    __syncthreads();
#pragma unroll
    for (int kk = 0; kk < 16; ++kk) {
      float4 af = *reinterpret_cast<const float4*>(&Asf[kk][ty * 4]);
      float4 bf = *reinterpret_cast<const float4*>(&Bsf[kk][tx * 4]);
      float a[4] = {af.x, af.y, af.z, af.w};
      float b[4] = {bf.x, bf.y, bf.z, bf.w};
#pragma unroll
      for (int i = 0; i < 4; ++i)
#pragma unroll
        for (int jj = 0; jj < 4; ++jj)
          acc[i][jj] = fmaf(a[i], b[jj], acc[i][jj]);
    }
    __syncthreads();
  }
#pragma unroll
  for (int i = 0; i < 4; ++i) {
    u64 bk = 0ull;
#pragma unroll
    for (int jj = 0; jj < 4; ++jj) {
      int col = n0 + tx * 4 + jj;
      if (col < N) {
        u64 pk = ((u64)fkey(acc[i][jj]) << 32) | (u32)(~(u32)col);
        if (pk > bk) bk = pk;
      }
    }
#pragma unroll
    for (int s = 1; s < 16; s <<= 1) {
      u64 o = __shfl_xor((unsigned long long)bk, s, 64);
      if (o > bk) bk = o;
    }
    if (tx == 0) atomicMax(&best[m0 + ty * 4 + i], bk);
  }
}

__global__ __launch_bounds__(256) void k2_decode(const u64* __restrict__ best,
                                                 int* __restrict__ r) {
  int i = blockIdx.x * 256 + threadIdx.x;
  if (i < M) r[i] = (int)(~(u32)(best[i] & 0xffffffffull));
}

__global__ __launch_bounds__(256) void k_mapall(u64* __restrict__ chunkmap) {
  int i = blockIdx.x * 256 + threadIdx.x;
  if (i < N) chunkmap[i] = ~0ull;
}

extern "C" void kernel_launch(void* const* d_in, const int* in_sizes, int n_in,
                              void* d_out, int out_size, void* d_ws, size_t ws_size,
                              hipStream_t stream) {
  const float* X = (const float*)d_in[0];
  const float* MU = (const float*)d_in[1];
  float* out = (float*)d_out;
  float* dis_slot = out + (size_t)N * K;

  if (ws_size >= WS_NEED) {
    unsigned short* A2 = (unsigned short*)((char*)d_ws + OFF_A2);
    unsigned short* B2 = (unsigned short*)((char*)d_ws + OFF_B2);
    u64* gtop = (u64*)((char*)d_ws + OFF_GTOP);
    u64* rbest = (u64*)((char*)d_ws + OFF_RB);
    int* r = (int*)((char*)d_ws + OFF_R);
    int* amb = (int*)((char*)d_ws + OFF_AMB);
    u32* wl = (u32*)((char*)d_ws + OFF_WL);
    u32* cnts = (u32*)((char*)d_ws + OFF_CNT);
    u64* chunkmap = (u64*)((char*)d_ws + OFF_CM);

    k_convx<<<8192, 256, 0, stream>>>(X, A2);
    k_convmu<<<NPAD, 256, 0, stream>>>(MU, B2, cnts, chunkmap, dis_slot);
    k_gemm<<<512 * NTIL, 256, 0, stream>>>(A2, B2, gtop);
    k_reduce<<<M / 256, 256, 0, stream>>>(gtop, r, amb, rbest, wl, cnts, chunkmap);
    k_refine<<<2048, 256, 0, stream>>>(X, MU, wl, cnts, rbest);
    k_decode2<<<MAXAMB / 256, 256, 0, stream>>>(amb, rbest, cnts, r, chunkmap);
    k_finalize<<<N, 256, 0, stream>>>(X, MU, r, chunkmap, out, dis_slot);
  } else {
    u64* best = (u64*)d_ws;
    int* r = (int*)((char*)d_ws + (size_t)M * sizeof(u64));
    u64* chunkmap = (u64*)((char*)d_ws + (size_t)M * 12);
    k0_init<<<M / 256, 256, 0, stream>>>(best, dis_slot);
    k_mapall<<<(N + 255) / 256, 256, 0, stream>>>(chunkmap);
    dim3 g1(M / 64, (N + 63) / 64);
    k1_f32<<<g1, 256, 0, stream>>>(X, MU, best);
    k2_decode<<<M / 256, 256, 0, stream>>>(best, r);
    k_finalize<<<N, 256, 0, stream>>>(X, MU, r, chunkmap, out, dis_slot);
  }
}

// Round 16
// 650.167 us; speedup vs baseline: 1.0644x; 1.0644x over previous
//
#include <hip/hip_runtime.h>
#include <hip/hip_bf16.h>

#define M 65536
#define N 3000
#define NPAD 3072
#define K 768
#define NT_K 24      // 768/32 K-slabs (BK=32)
#define NTIL 24      // 3072 / 128 n-tiles
#define KSP 128
#define MAXL 8192
#define GAPTHR 4.5e-3f
#define MAXAMB 16384
#define MAXWL 196608
#define NEGINF -3.4e38f

typedef __attribute__((ext_vector_type(8))) _Float16 f16x8;
typedef __attribute__((ext_vector_type(4))) float f32x4;
typedef unsigned long long u64;
typedef unsigned int u32;

#define AS1 __attribute__((address_space(1)))
#define AS3 __attribute__((address_space(3)))

// ws layout (bytes)
#define OFF_A2   0ull            // M*768*2   = 100663296
#define OFF_B2   100663296ull    // 3072*768*2 = 4718592
#define OFF_GTOP 105381888ull    // M*24*2*8  = 25165824
#define OFF_RB   130547712ull    // M*8       = 524288
#define OFF_R    131072000ull    // M*4       = 262144
#define OFF_AMB  131334144ull    // 16384*4
#define OFF_WL   131465216ull    // 196608*4  = 786432
#define OFF_CNT  132251648ull    // 2 u32 (+pad)
#define OFF_CM   132251904ull    // 3072*8 = 24576 chunk bitmaps
#define WS_NEED  132276480ull

__device__ inline unsigned short f2h(float x) {
  _Float16 h = (_Float16)x;
  return *reinterpret_cast<unsigned short*>(&h);
}
__device__ inline u32 fkey(float v) {
  u32 ub = __float_as_uint(v);
  return (ub & 0x80000000u) ? ~ub : (ub | 0x80000000u);
}
__device__ inline float keyf(u32 key) {
  u32 ub = (key & 0x80000000u) ? (key ^ 0x80000000u) : ~key;
  return __uint_as_float(ub);
}
__device__ inline void gload16(const void* g, void* l) {
  __builtin_amdgcn_global_load_lds((AS1 u32*)g, (AS3 u32*)l, 16, 0, 0);
}

// ---------------- K0a: X -> fp16 ----------------
__global__ __launch_bounds__(256) void k_convx(const float* __restrict__ X,
                                               unsigned short* __restrict__ A2) {
  const int tot = M * (K / 8);
  for (int i = blockIdx.x * 256 + threadIdx.x; i < tot; i += gridDim.x * 256) {
    size_t base = (size_t)i * 8;
    float4 v0 = *reinterpret_cast<const float4*>(X + base);
    float4 v1 = *reinterpret_cast<const float4*>(X + base + 4);
    ushort4 h0, h1;
    h0.x = f2h(v0.x); h0.y = f2h(v0.y); h0.z = f2h(v0.z); h0.w = f2h(v0.w);
    h1.x = f2h(v1.x); h1.y = f2h(v1.y); h1.z = f2h(v1.z); h1.w = f2h(v1.w);
    *reinterpret_cast<ushort4*>(A2 + base) = h0;
    *reinterpret_cast<ushort4*>(A2 + base + 4) = h1;
  }
}

// ---------------- K0b: MU -> fp16, pad rows zero; reset counters/maps -------
__global__ __launch_bounds__(256) void k_convmu(const float* __restrict__ MU,
                                                unsigned short* __restrict__ B2,
                                                u32* __restrict__ cnts,
                                                u64* __restrict__ chunkmap,
                                                float* __restrict__ dis_slot) {
  int j = blockIdx.x, t = threadIdx.x;
  if (j == 0 && t == 0) { cnts[0] = 0u; cnts[1] = 0u; }
  if (j == 0 && t == 1) *dis_slot = 0.0f;
  if (t == 2 && j < N) chunkmap[j] = 0ull;
  for (int c = t; c < K; c += 256) {
    float x = (j < N) ? MU[(size_t)j * K + c] : 0.0f;
    B2[(size_t)j * K + c] = f2h(x);
  }
}

// ---------------- K1: 128x128 4-wave, BK=32, 32KiB LDS, 4 blocks/CU ---------
// EXACT R10/R13/R14 configuration (verified 415us, 56 VGPR, 0 conflicts).
// [R11/R12 lesson: min-waves 5/6 -> acc spill. R15 lesson: 3-buf/1-barrier
// drops to 3 blocks/CU and regresses — cross-block decoupling at 4 blocks/CU
// is the dominant stall-hider. Keep this config frozen.]
__global__ __launch_bounds__(256, 4) void k_gemm(const unsigned short* __restrict__ A2,
                                                 const unsigned short* __restrict__ B2,
                                                 u64* __restrict__ gtop) {
  __shared__ unsigned short smem[16384];  // 32 KiB: A[2][4096], B[2][4096]

  const int bid = blockIdx.x;
  const int xcd = bid & 7, idx = bid >> 3;
  const int g = idx / 96, rem = idx % 96;
  const int nt = rem >> 2, mi = rem & 3;
  const int mt = xcd * 64 + g * 4 + mi;
  const int m0 = mt * 128, n0 = nt * 128;

  const int t = threadIdx.x;
  const int w = t >> 6, ln = t & 63;
  const int wr = w >> 1, wc = w & 1;          // 2M x 2N waves
  const int li = ln & 15, lg = ln >> 4;

  const int r0 = t >> 2;
  const int c0 = ((t & 3) ^ ((t >> 3) & 3)) * 8;
  const unsigned short* pa0 = A2 + (size_t)(m0 + r0) * K + c0;
  const unsigned short* pb0 = B2 + (size_t)(n0 + r0) * K + c0;

  f32x4 acc[4][4] = {};

  const int rA = wr * 64 + li;
  const int rB = wc * 64 + li;
  const int cc = (lg ^ ((li >> 1) & 3)) * 8;  // read-side swizzled chunk

#define STAGE(kt_, p_)                                                        \
  {                                                                           \
    int k0_ = (kt_) * 32;                                                     \
    gload16(pa0 + k0_, smem + (p_) * 4096 + t * 8);                           \
    gload16(pa0 + (size_t)64 * K + k0_, smem + (p_) * 4096 + 2048 + t * 8);   \
    gload16(pb0 + k0_, smem + 8192 + (p_) * 4096 + t * 8);                    \
    gload16(pb0 + (size_t)64 * K + k0_,                                       \
            smem + 8192 + (p_) * 4096 + 2048 + t * 8);                        \
  }

  STAGE(0, 0);
  STAGE(1, 1);

  for (int kt = 0; kt < NT_K; ++kt) {
    const int p = kt & 1;
    if (kt >= NT_K - 1)
      asm volatile("s_waitcnt vmcnt(0)" ::: "memory");
    else
      asm volatile("s_waitcnt vmcnt(4)" ::: "memory");
    __builtin_amdgcn_s_barrier();
    asm volatile("" ::: "memory");

    const unsigned short* baseA = smem + p * 4096;
    const unsigned short* baseB = smem + 8192 + p * 4096;
    f16x8 aa[4], bb[4];
#pragma unroll
    for (int n_ = 0; n_ < 4; ++n_)
      bb[n_] = *reinterpret_cast<const f16x8*>(baseB + (rB + n_ * 16) * 32 + cc);
#pragma unroll
    for (int m_ = 0; m_ < 4; ++m_)
      aa[m_] = *reinterpret_cast<const f16x8*>(baseA + (rA + m_ * 16) * 32 + cc);

    __builtin_amdgcn_s_setprio(1);
#pragma unroll
    for (int m_ = 0; m_ < 4; ++m_)
#pragma unroll
      for (int n_ = 0; n_ < 4; ++n_)
        acc[m_][n_] = __builtin_amdgcn_mfma_f32_16x16x32_f16(
            aa[m_], bb[n_], acc[m_][n_], 0, 0, 0);
    __builtin_amdgcn_s_setprio(0);

    asm volatile("s_waitcnt lgkmcnt(0)" ::: "memory");
    __builtin_amdgcn_s_barrier();
    asm volatile("" ::: "memory");
    if (kt < NT_K - 2) STAGE(kt + 2, p);
  }

  // ---- epilogue: per-row top2 via f32 butterflies ----
  u64* stop = reinterpret_cast<u64*>(smem);  // [2][128][2] u64 = 4KB
#pragma unroll
  for (int m = 0; m < 4; ++m)
#pragma unroll
    for (int reg = 0; reg < 4; ++reg) {
      float l1 = NEGINF, l2 = NEGINF;
      int nb = 0;
#pragma unroll
      for (int n = 0; n < 4; ++n) {
        int col = n0 + wc * 64 + n * 16 + li;
        float v = (col < N) ? acc[m][n][reg] : NEGINF;
        if (v > l1) { l2 = l1; l1 = v; nb = n; }
        else if (v > l2) l2 = v;
      }
      const float loc1 = l1;
#pragma unroll
      for (int s = 1; s < 16; s <<= 1) {
        float o1 = __shfl_xor(l1, s, 64);
        float o2 = __shfl_xor(l2, s, 64);
        float hi = fmaxf(l1, o1);
        float lo = fminf(l1, o1);
        l2 = fmaxf(lo, fmaxf(l2, o2));
        l1 = hi;
      }
      unsigned long long bal = __ballot(loc1 == l1);
      unsigned mask16 = (unsigned)(bal >> (lg * 16)) & 0xffffu;
      int first = __builtin_ctz(mask16 | 0x10000u);
      int nbo = __shfl(nb, lg * 16 + first, 64);
      int col1 = n0 + wc * 64 + nbo * 16 + first;
      if (li == 0) {
        int rloc = wr * 64 + m * 16 + lg * 4 + reg;
        stop[(wc * 128 + rloc) * 2 + 0] =
            ((u64)fkey(l1) << 32) | (u32)(~(u32)col1);
        stop[(wc * 128 + rloc) * 2 + 1] = ((u64)fkey(l2) << 32);
      }
    }
  __syncthreads();
  if (t < 128) {
    u64 g1 = 0, g2 = 0;
#pragma unroll
    for (int q = 0; q < 2; ++q) {
      u64 a1 = stop[(q * 128 + t) * 2 + 0], a2 = stop[(q * 128 + t) * 2 + 1];
      u64 n1 = g1 > a1 ? g1 : a1;
      u64 lo = g1 > a1 ? a1 : g1;
      u64 mx = g2 > a2 ? g2 : a2;
      g2 = lo > mx ? lo : mx;
      g1 = n1;
    }
    u64* dst = gtop + ((size_t)(m0 + t) * NTIL + nt) * 2;
    dst[0] = g1;
    dst[1] = g2;
  }
}

// ---------------- K2: merge 24 tiles -> r, worklist + chunk bitmap ----------
__global__ __launch_bounds__(256) void k_reduce(const u64* __restrict__ gtop,
                                                int* __restrict__ r,
                                                int* __restrict__ amb,
                                                u64* __restrict__ rbest,
                                                u32* __restrict__ wl,
                                                u32* __restrict__ cnts,
                                                u64* __restrict__ chunkmap) {
  int row = blockIdx.x * 256 + threadIdx.x;
  if (row >= M) return;
  const u64* src = gtop + (size_t)row * NTIL * 2;
  u64 tops[NTIL];
  u64 g1 = 0, g2 = 0;
#pragma unroll
  for (int tt = 0; tt < NTIL; ++tt) {
    u64 a1 = src[tt * 2], a2 = src[tt * 2 + 1];
    tops[tt] = a1;
    u64 n1 = g1 > a1 ? g1 : a1;
    u64 lo = g1 > a1 ? a1 : g1;
    u64 mx = g2 > a2 ? g2 : a2;
    g2 = lo > mx ? lo : mx;
    g1 = n1;
  }
  int jbest = (int)(~(u32)(g1 & 0xffffffffull));
  r[row] = jbest;
  atomicOr(&chunkmap[jbest], 1ull << (row >> 10));
  float v1 = keyf((u32)(g1 >> 32)), v2 = keyf((u32)(g2 >> 32));
  if (v1 - v2 < GAPTHR) {
    u32 idx = atomicAdd(&cnts[0], 1u);
    if (idx < MAXAMB) {
      amb[idx] = row;
      rbest[row] = 0ull;
      float thr = v1 - GAPTHR;
#pragma unroll
      for (int tt = 0; tt < NTIL; ++tt) {
        if (keyf((u32)(tops[tt] >> 32)) >= thr) {
          u32 wi = atomicAdd(&cnts[1], 1u);
          if (wi < MAXWL) wl[wi] = ((u32)row << 5) | (u32)tt;
        }
      }
    }
  }
}

// ---------------- K3: exact fp32 re-argmax over compact worklist ------------
__global__ __launch_bounds__(256) void k_refine(const float* __restrict__ X,
                                                const float* __restrict__ MU,
                                                const u32* __restrict__ wl,
                                                const u32* __restrict__ cnts,
                                                u64* __restrict__ rbest) {
  __shared__ float xrow[768];
  __shared__ u64 wb[4];
  const int t = threadIdx.x, w = t >> 6, ln = t & 63;
  const int nw = (int)min(cnts[1], (u32)MAXWL);
  for (int u = blockIdx.x; u < nw; u += gridDim.x) {
    const u32 e = wl[u];
    const int row = (int)(e >> 5), tile = (int)(e & 31);

    xrow[t] = X[(size_t)row * K + t];
    xrow[t + 256] = X[(size_t)row * K + t + 256];
    xrow[t + 512] = X[(size_t)row * K + t + 512];
    __syncthreads();

    u64 best = 0;
    for (int q = 0; q < 8; ++q) {
      const int cbase = tile * 128 + w * 32 + q * 4;
      const float* m0p = MU + (size_t)min(cbase + 0, N - 1) * K;
      const float* m1p = MU + (size_t)min(cbase + 1, N - 1) * K;
      const float* m2p = MU + (size_t)min(cbase + 2, N - 1) * K;
      const float* m3p = MU + (size_t)min(cbase + 3, N - 1) * K;
      float p0 = 0.f, p1 = 0.f, p2 = 0.f, p3 = 0.f;
#pragma unroll
      for (int it = 0; it < 3; ++it) {
        int d4 = (ln + it * 64) * 4;
        float4 xv = *reinterpret_cast<const float4*>(&xrow[d4]);
        float4 a0 = *reinterpret_cast<const float4*>(m0p + d4);
        float4 a1 = *reinterpret_cast<const float4*>(m1p + d4);
        float4 a2 = *reinterpret_cast<const float4*>(m2p + d4);
        float4 a3 = *reinterpret_cast<const float4*>(m3p + d4);
        p0 += xv.x * a0.x + xv.y * a0.y + xv.z * a0.z + xv.w * a0.w;
        p1 += xv.x * a1.x + xv.y * a1.y + xv.z * a1.z + xv.w * a1.w;
        p2 += xv.x * a2.x + xv.y * a2.y + xv.z * a2.z + xv.w * a2.w;
        p3 += xv.x * a3.x + xv.y * a3.y + xv.z * a3.z + xv.w * a3.w;
      }
#pragma unroll
      for (int s = 32; s; s >>= 1) {
        p0 += __shfl_xor(p0, s, 64);
        p1 += __shfl_xor(p1, s, 64);
        p2 += __shfl_xor(p2, s, 64);
        p3 += __shfl_xor(p3, s, 64);
      }
      if (ln == 0) {
        float ps[4] = {p0, p1, p2, p3};
#pragma unroll
        for (int i = 0; i < 4; ++i) {
          int c = cbase + i;
          if (c < N) {
            u64 pk = ((u64)fkey(ps[i]) << 32) | (u32)(~(u32)c);
            if (pk > best) best = pk;
          }
        }
      }
    }
    if (ln == 0) wb[w] = best;
    __syncthreads();
    if (t == 0) {
      u64 b = wb[0];
#pragma unroll
      for (int i = 1; i < 4; ++i)
        if (wb[i] > b) b = wb[i];
      atomicMax(&rbest[row], b);
    }
    __syncthreads();
  }
}

// ---------------- K3b: decode refined assignments (+bitmap update) ----------
__global__ __launch_bounds__(256) void k_decode2(const int* __restrict__ amb,
                                                 const u64* __restrict__ rbest,
                                                 const u32* __restrict__ cnts,
                                                 int* __restrict__ r,
                                                 u64* __restrict__ chunkmap) {
  int i = blockIdx.x * 256 + threadIdx.x;
  int n_amb = (int)min(cnts[0], (u32)MAXAMB);
  if (i < n_amb) {
    int row = amb[i];
    int jn = (int)(~(u32)(rbest[row] & 0xffffffffull));
    r[row] = jn;
    atomicOr(&chunkmap[jn], 1ull << (row >> 10));
  }
}

// ---------------- K4: finalize (chunk-bitmap skip + ILP member sum) ---------
__global__ __launch_bounds__(256) void k_finalize(const float* __restrict__ X,
                                                  const float* __restrict__ MU,
                                                  const int* __restrict__ r,
                                                  const u64* __restrict__ chunkmap,
                                                  float* __restrict__ out,
                                                  float* __restrict__ dis_slot) {
#pragma clang fp contract(off)
  const int j = blockIdx.x;
  const int t = threadIdx.x;
  const int lane = t & 63;
  const int wid = t >> 6;
  __shared__ int list[MAXL];
  __shared__ int wc4[4][4];   // [wave][group]
  __shared__ float red[4];
  __shared__ unsigned hist[256];
  __shared__ int selI;

  const u64 cmap = chunkmap[j];
  int cnt = 0;
  for (int ch = 0; ch < 64; ++ch) {
    if (!((cmap >> ch) & 1ull)) continue;  // block-uniform skip
    const int base = ch << 10;
    bool f[4];
    u64 bm[4];
#pragma unroll
    for (int q = 0; q < 4; ++q) {
      f[q] = (r[base + q * 256 + t] == j);
      bm[q] = __ballot(f[q]);
    }
    if (lane == 0) {
#pragma unroll
      for (int q = 0; q < 4; ++q) wc4[wid][q] = __popcll(bm[q]);
    }
    __syncthreads();
    int goff = cnt;
#pragma unroll
    for (int q = 0; q < 4; ++q) {
      if (f[q]) {
        int off = goff;
        for (int ww = 0; ww < wid; ++ww) off += wc4[ww][q];
        int pos = off + __popcll(bm[q] & ((1ull << lane) - 1ull));
        if (pos < MAXL) list[pos] = base + q * 256 + t;
      }
      goff += wc4[0][q] + wc4[1][q] + wc4[2][q] + wc4[3][q];
    }
    cnt = goff;
    __syncthreads();
  }
  int cl = cnt < MAXL ? cnt : MAXL;

  // member sums: 4 independent accumulator chains (ILP), fixed-order combine
  float a0 = 0.f, a1 = 0.f, a2 = 0.f, a3 = 0.f;
  float b0 = 0.f, b1 = 0.f, b2 = 0.f, b3 = 0.f;
  float c0 = 0.f, c1 = 0.f, c2 = 0.f, c3 = 0.f;
  int m = 0;
  for (; m + 3 < cl; m += 4) {
    const float* x0 = X + (size_t)list[m + 0] * K;
    const float* x1 = X + (size_t)list[m + 1] * K;
    const float* x2 = X + (size_t)list[m + 2] * K;
    const float* x3 = X + (size_t)list[m + 3] * K;
    a0 += x0[t]; b0 += x0[t + 256]; c0 += x0[t + 512];
    a1 += x1[t]; b1 += x1[t + 256]; c1 += x1[t + 512];
    a2 += x2[t]; b2 += x2[t + 256]; c2 += x2[t + 512];
    a3 += x3[t]; b3 += x3[t + 256]; c3 += x3[t + 512];
  }
  for (; m < cl; ++m) {
    const float* xr = X + (size_t)list[m] * K;
    a0 += xr[t]; b0 += xr[t + 256]; c0 += xr[t + 512];
  }
  float s0 = ((a0 + a1) + a2) + a3;
  float s1 = ((b0 + b1) + b2) + b3;
  float s2 = ((c0 + c1) + c2) + c3;

  const float mu0 = MU[(size_t)j * K + t];
  const float mu1 = MU[(size_t)j * K + t + 256];
  const float mu2 = MU[(size_t)j * K + t + 512];

  float u0, u1, u2;
  if (cnt >= 1) {
    float c = (float)cnt;
    u0 = s0 / c; u1 = s1 / c; u2 = s2 / c;
  } else {
    u0 = mu0; u1 = mu1; u2 = mu2;
  }
  float v0 = u0 * 0.2f + mu0 * 0.8f;
  float v1 = u1 * 0.2f + mu1 * 0.8f;
  float v2 = u2 * 0.2f + mu2 * 0.8f;

  float ss = v0 * v0 + v1 * v1 + v2 * v2;
#pragma unroll
  for (int s = 32; s > 0; s >>= 1) ss += __shfl_down(ss, s, 64);
  if (lane == 0) red[wid] = ss;
  __syncthreads();
  float tot = red[0] + red[1] + red[2] + red[3];
  float den = sqrtf(tot);
  den = fmaxf(den, 1e-12f);
  float un0 = v0 / den, un1 = v1 / den, un2 = v2 / den;
  unsigned k0b = __float_as_uint(fabsf(un0));
  unsigned k1b = __float_as_uint(fabsf(un1));
  unsigned k2b = __float_as_uint(fabsf(un2));
  __syncthreads();

  unsigned cur = 0;
  int need = KSP;
  for (int sh = 24; sh >= 0; sh -= 8) {
    hist[t] = 0u;
    if (t == 0) selI = -1;
    __syncthreads();
    bool m0_ = (sh == 24) || ((k0b >> (sh + 8)) == (cur >> (sh + 8)));
    bool m1_ = (sh == 24) || ((k1b >> (sh + 8)) == (cur >> (sh + 8)));
    bool m2_ = (sh == 24) || ((k2b >> (sh + 8)) == (cur >> (sh + 8)));
    if (m0_) atomicAdd(&hist[(k0b >> sh) & 255u], 1u);
    if (m1_) atomicAdd(&hist[(k1b >> sh) & 255u], 1u);
    if (m2_) atomicAdd(&hist[(k2b >> sh) & 255u], 1u);
    __syncthreads();
#pragma unroll
    for (int off = 1; off < 256; off <<= 1) {
      unsigned nb = (t + off < 256) ? hist[t + off] : 0u;
      __syncthreads();
      hist[t] += nb;
      __syncthreads();
    }
    if (hist[t] >= (unsigned)need) atomicMax(&selI, t);
    __syncthreads();
    int b = selI < 0 ? 0 : selI;
    unsigned above = (b < 255) ? hist[b + 1] : 0u;
    cur |= ((unsigned)b << sh);
    need = need - (int)above;
    __syncthreads();
  }
  unsigned th = cur;

  float o0 = (k0b >= th) ? un0 : 0.0f;
  float o1 = (k1b >= th) ? un1 : 0.0f;
  float o2 = (k2b >= th) ? un2 : 0.0f;
  out[(size_t)j * K + t] = o0;
  out[(size_t)j * K + t + 256] = o1;
  out[(size_t)j * K + t + 512] = o2;

  float q0 = o0 - mu0, q1 = o1 - mu1, q2 = o2 - mu2;
  float dq = q0 * q0 + q1 * q1 + q2 * q2;
#pragma unroll
  for (int s = 32; s > 0; s >>= 1) dq += __shfl_down(dq, s, 64);
  __syncthreads();
  if (lane == 0) red[wid] = dq;
  __syncthreads();
  if (t == 0) {
    float dtot = red[0] + red[1] + red[2] + red[3];
    float dn = sqrtf(dtot);
    atomicMax((unsigned*)dis_slot, __float_as_uint(dn));
  }
}

// ================= fallback fp32 path (ws too small) =================
__global__ __launch_bounds__(256) void k0_init(u64* __restrict__ best,
                                               float* __restrict__ dis_slot) {
  int i = blockIdx.x * 256 + threadIdx.x;
  if (i < M) best[i] = 0ull;
  if (i == 0) *dis_slot = 0.0f;
}

__global__ __launch_bounds__(256) void k1_f32(const float* __restrict__ X,
                                              const float* __restrict__ MU,
                                              u64* __restrict__ best) {
  __shared__ float Asf[16][64];
  __shared__ float Bsf[16][64];
  const int m0 = blockIdx.x * 64;
  const int n0 = blockIdx.y * 64;
  const int t = threadIdx.x;
  const int tx = t & 15, ty = t >> 4;
  const int lrow = t >> 2, lcg = t & 3;

  float acc[4][4];
#pragma unroll
  for (int i = 0; i < 4; ++i)
#pragma unroll
    for (int jj = 0; jj < 4; ++jj) acc[i][jj] = 0.0f;

  const float* aptr = X + (size_t)(m0 + lrow) * K + lcg * 4;
  const bool bvalid = (n0 + lrow) < N;
  const float* bptr = MU + (size_t)(bvalid ? (n0 + lrow) : 0) * K + lcg * 4;

  for (int k0 = 0; k0 < K; k0 += 16) {
    float4 av = *reinterpret_cast<const float4*>(aptr + k0);
    float4 bv = make_float4(0.f, 0.f, 0.f, 0.f);
    if (bvalid) bv = *reinterpret_cast<const float4*>(bptr + k0);
    Asf[lcg * 4 + 0][lrow] = av.x; Asf[lcg * 4 + 1][lrow] = av.y;
    Asf[lcg * 4 + 2][lrow] = av.z; Asf[lcg * 4 + 3][lrow] = av.w;
    Bsf[lcg * 4 + 0][lrow] = bv.x; Bsf[lcg * 4 + 1][lrow] = bv.y;
    Bsf[lcg * 4 + 2][lrow] = bv.z; Bsf[lcg * 4 + 3][lrow] = bv.w;
    __syncthreads();
#pragma unroll
    for (int kk = 0; kk < 16; ++kk) {
      float4 af = *reinterpret_cast<const float4*>(&Asf[kk][ty * 4]);
      float4 bf = *reinterpret_cast<const float4*>(&Bsf[kk][tx * 4]);
      float a[4] = {af.x, af.y, af.z, af.w};
      float b[4] = {bf.x, bf.y, bf.z, bf.w};
#pragma unroll
      for (int i = 0; i < 4; ++i)
#pragma unroll
        for (int jj = 0; jj < 4; ++jj)
          acc[i][jj] = fmaf(a[i], b[jj], acc[i][jj]);
    }
    __syncthreads();
  }
#pragma unroll
  for (int i = 0; i < 4; ++i) {
    u64 bk = 0ull;
#pragma unroll
    for (int jj = 0; jj < 4; ++jj) {
      int col = n0 + tx * 4 + jj;
      if (col < N) {
        u64 pk = ((u64)fkey(acc[i][jj]) << 32) | (u32)(~(u32)col);
        if (pk > bk) bk = pk;
      }
    }
#pragma unroll
    for (int s = 1; s < 16; s <<= 1) {
      u64 o = __shfl_xor((unsigned long long)bk, s, 64);
      if (o > bk) bk = o;
    }
    if (tx == 0) atomicMax(&best[m0 + ty * 4 + i], bk);
  }
}

__global__ __launch_bounds__(256) void k2_decode(const u64* __restrict__ best,
                                                 int* __restrict__ r) {
  int i = blockIdx.x * 256 + threadIdx.x;
  if (i < M) r[i] = (int)(~(u32)(best[i] & 0xffffffffull));
}

__global__ __launch_bounds__(256) void k_mapall(u64* __restrict__ chunkmap) {
  int i = blockIdx.x * 256 + threadIdx.x;
  if (i < N) chunkmap[i] = ~0ull;
}

extern "C" void kernel_launch(void* const* d_in, const int* in_sizes, int n_in,
                              void* d_out, int out_size, void* d_ws, size_t ws_size,
                              hipStream_t stream) {
  const float* X = (const float*)d_in[0];
  const float* MU = (const float*)d_in[1];
  float* out = (float*)d_out;
  float* dis_slot = out + (size_t)N * K;

  if (ws_size >= WS_NEED) {
    unsigned short* A2 = (unsigned short*)((char*)d_ws + OFF_A2);
    unsigned short* B2 = (unsigned short*)((char*)d_ws + OFF_B2);
    u64* gtop = (u64*)((char*)d_ws + OFF_GTOP);
    u64* rbest = (u64*)((char*)d_ws + OFF_RB);
    int* r = (int*)((char*)d_ws + OFF_R);
    int* amb = (int*)((char*)d_ws + OFF_AMB);
    u32* wl = (u32*)((char*)d_ws + OFF_WL);
    u32* cnts = (u32*)((char*)d_ws + OFF_CNT);
    u64* chunkmap = (u64*)((char*)d_ws + OFF_CM);

    k_convx<<<8192, 256, 0, stream>>>(X, A2);
    k_convmu<<<NPAD, 256, 0, stream>>>(MU, B2, cnts, chunkmap, dis_slot);
    k_gemm<<<512 * NTIL, 256, 0, stream>>>(A2, B2, gtop);
    k_reduce<<<M / 256, 256, 0, stream>>>(gtop, r, amb, rbest, wl, cnts, chunkmap);
    k_refine<<<2048, 256, 0, stream>>>(X, MU, wl, cnts, rbest);
    k_decode2<<<MAXAMB / 256, 256, 0, stream>>>(amb, rbest, cnts, r, chunkmap);
    k_finalize<<<N, 256, 0, stream>>>(X, MU, r, chunkmap, out, dis_slot);
  } else {
    u64* best = (u64*)d_ws;
    int* r = (int*)((char*)d_ws + (size_t)M * sizeof(u64));
    u64* chunkmap = (u64*)((char*)d_ws + (size_t)M * 12);
    k0_init<<<M / 256, 256, 0, stream>>>(best, dis_slot);
    k_mapall<<<(N + 255) / 256, 256, 0, stream>>>(chunkmap);
    dim3 g1(M / 64, (N + 63) / 64);
    k1_f32<<<g1, 256, 0, stream>>>(X, MU, best);
    k2_decode<<<M / 256, 256, 0, stream>>>(best, r);
    k_finalize<<<N, 256, 0, stream>>>(X, MU, r, chunkmap, out, dis_slot);
  }
}

// Round 17
// 643.270 us; speedup vs baseline: 1.0758x; 1.0107x over previous
//
#include <hip/hip_runtime.h>
#include <hip/hip_bf16.h>

#define M 65536
#define N 3000
#define NPAD 3072
#define K 768
#define NT_K 24      // 768/32 K-slabs (BK=32)
#define NTIL 24      // 3072 / 128 n-tiles
#define KSP 128
#define MAXL 8192
#define GAPTHR 4.5e-3f
#define MAXAMB 16384
#define MAXWL 196608
#define NEGINF -3.4e38f

typedef __attribute__((ext_vector_type(8))) _Float16 f16x8;
typedef __attribute__((ext_vector_type(4))) float f32x4;
typedef unsigned long long u64;
typedef unsigned int u32;

#define AS1 __attribute__((address_space(1)))
#define AS3 __attribute__((address_space(3)))

// ws layout (bytes)
#define OFF_A2   0ull            // M*768*2   = 100663296
#define OFF_B2   100663296ull    // 3072*768*2 = 4718592
#define OFF_GTOP 105381888ull    // M*24*2*8  = 25165824
#define OFF_RB   130547712ull    // M*8       = 524288
#define OFF_R    131072000ull    // M*4       = 262144
#define OFF_AMB  131334144ull    // 16384*4
#define OFF_WL   131465216ull    // 196608*4  = 786432
#define OFF_CNT  132251648ull    // 2 u32 (+pad)
#define OFF_CM   132251904ull    // 3072*8 = 24576 chunk bitmaps
#define WS_NEED  132276480ull

__device__ inline unsigned short f2h(float x) {
  _Float16 h = (_Float16)x;
  return *reinterpret_cast<unsigned short*>(&h);
}
__device__ inline u32 fkey(float v) {
  u32 ub = __float_as_uint(v);
  return (ub & 0x80000000u) ? ~ub : (ub | 0x80000000u);
}
__device__ inline float keyf(u32 key) {
  u32 ub = (key & 0x80000000u) ? (key ^ 0x80000000u) : ~key;
  return __uint_as_float(ub);
}
__device__ inline void gload16(const void* g, void* l) {
  __builtin_amdgcn_global_load_lds((AS1 u32*)g, (AS3 u32*)l, 16, 0, 0);
}

// ---------------- K0a: X -> fp16 ----------------
__global__ __launch_bounds__(256) void k_convx(const float* __restrict__ X,
                                               unsigned short* __restrict__ A2) {
  const int tot = M * (K / 8);
  for (int i = blockIdx.x * 256 + threadIdx.x; i < tot; i += gridDim.x * 256) {
    size_t base = (size_t)i * 8;
    float4 v0 = *reinterpret_cast<const float4*>(X + base);
    float4 v1 = *reinterpret_cast<const float4*>(X + base + 4);
    ushort4 h0, h1;
    h0.x = f2h(v0.x); h0.y = f2h(v0.y); h0.z = f2h(v0.z); h0.w = f2h(v0.w);
    h1.x = f2h(v1.x); h1.y = f2h(v1.y); h1.z = f2h(v1.z); h1.w = f2h(v1.w);
    *reinterpret_cast<ushort4*>(A2 + base) = h0;
    *reinterpret_cast<ushort4*>(A2 + base + 4) = h1;
  }
}

// ---------------- K0b: MU -> fp16, pad rows zero; reset counters/maps -------
__global__ __launch_bounds__(256) void k_convmu(const float* __restrict__ MU,
                                                unsigned short* __restrict__ B2,
                                                u32* __restrict__ cnts,
                                                u64* __restrict__ chunkmap,
                                                float* __restrict__ dis_slot) {
  int j = blockIdx.x, t = threadIdx.x;
  if (j == 0 && t == 0) { cnts[0] = 0u; cnts[1] = 0u; }
  if (j == 0 && t == 1) *dis_slot = 0.0f;
  if (t == 2 && j < N) chunkmap[j] = 0ull;
  for (int c = t; c < K; c += 256) {
    float x = (j < N) ? MU[(size_t)j * K + c] : 0.0f;
    B2[(size_t)j * K + c] = f2h(x);
  }
}

// ---------------- K1: 256x128 8-wave, BK=32, 48KiB LDS, 3 blocks/CU ---------
// R10's verified 2-barrier schedule with wave shape UNCHANGED (64x64/wave,
// 4+4 ds_reads, 16 MFMAs, same swizzle); only block M-extent doubled.
// NO launch_bounds min-waves (R11's spill was bound-induced, not geometric).
// STAGE = 3 gloads/thread (A 2 + B 1) -> steady vmcnt(3).
__global__ __launch_bounds__(512) void k_gemm(const unsigned short* __restrict__ A2,
                                              const unsigned short* __restrict__ B2,
                                              u64* __restrict__ gtop) {
  __shared__ unsigned short smem[24576];  // 48 KiB: A[2][8192], B[2][4096]

  // grid: 6144 = 256 mt x 24 nt; 8 XCD chunks of 32 mt; 4-mt supergroups.
  const int bid = blockIdx.x;
  const int xcd = bid & 7, idx = bid >> 3;
  const int g = idx / 96, rem = idx % 96;
  const int nt = rem >> 2, mi = rem & 3;
  const int mt = xcd * 32 + g * 4 + mi;
  const int m0 = mt * 256, n0 = nt * 128;

  const int t = threadIdx.x;
  const int w = t >> 6, ln = t & 63;
  const int wr = w >> 1, wc = w & 1;          // 4M x 2N waves, 64x64 each
  const int li = ln & 15, lg = ln >> 4;

  // staging: thread t covers A rows r0 (t>>2) and r0+128, B row r0; 16B chunk
  // (t&3); source pre-swizzled by ((row>>1)&3) ((row+128)>>1 preserves &3).
  const int r0 = t >> 2;
  const int c0 = ((t & 3) ^ ((t >> 3) & 3)) * 8;
  const unsigned short* pa0 = A2 + (size_t)(m0 + r0) * K + c0;
  const unsigned short* pb0 = B2 + (size_t)(n0 + r0) * K + c0;

  f32x4 acc[4][4] = {};

  const int rA = wr * 64 + li;   // row in 256
  const int rB = wc * 64 + li;   // row in 128
  const int cc = (lg ^ ((li >> 1) & 3)) * 8;  // read-side swizzled chunk

#define STAGE(kt_, p_)                                                        \
  {                                                                           \
    int k0_ = (kt_) * 32;                                                     \
    gload16(pa0 + k0_, smem + (p_) * 8192 + t * 8);                           \
    gload16(pa0 + (size_t)128 * K + k0_, smem + (p_) * 8192 + 4096 + t * 8);  \
    gload16(pb0 + k0_, smem + 16384 + (p_) * 4096 + t * 8);                   \
  }

  STAGE(0, 0);
  STAGE(1, 1);

  for (int kt = 0; kt < NT_K; ++kt) {
    const int p = kt & 1;
    if (kt >= NT_K - 1)
      asm volatile("s_waitcnt vmcnt(0)" ::: "memory");
    else
      asm volatile("s_waitcnt vmcnt(3)" ::: "memory");
    __builtin_amdgcn_s_barrier();
    asm volatile("" ::: "memory");

    const unsigned short* baseA = smem + p * 8192;
    const unsigned short* baseB = smem + 16384 + p * 4096;
    f16x8 aa[4], bb[4];
#pragma unroll
    for (int n_ = 0; n_ < 4; ++n_)
      bb[n_] = *reinterpret_cast<const f16x8*>(baseB + (rB + n_ * 16) * 32 + cc);
#pragma unroll
    for (int m_ = 0; m_ < 4; ++m_)
      aa[m_] = *reinterpret_cast<const f16x8*>(baseA + (rA + m_ * 16) * 32 + cc);

    __builtin_amdgcn_s_setprio(1);
#pragma unroll
    for (int m_ = 0; m_ < 4; ++m_)
#pragma unroll
      for (int n_ = 0; n_ < 4; ++n_)
        acc[m_][n_] = __builtin_amdgcn_mfma_f32_16x16x32_f16(
            aa[m_], bb[n_], acc[m_][n_], 0, 0, 0);
    __builtin_amdgcn_s_setprio(0);

    asm volatile("s_waitcnt lgkmcnt(0)" ::: "memory");
    __builtin_amdgcn_s_barrier();
    asm volatile("" ::: "memory");
    if (kt < NT_K - 2) STAGE(kt + 2, p);
  }

  // ---- epilogue: per-row top2 via f32 butterflies ----
  u64* stop = reinterpret_cast<u64*>(smem);  // [2][256][2] u64 = 8KB
#pragma unroll
  for (int m = 0; m < 4; ++m)
#pragma unroll
    for (int reg = 0; reg < 4; ++reg) {
      float l1 = NEGINF, l2 = NEGINF;
      int nb = 0;
#pragma unroll
      for (int n = 0; n < 4; ++n) {
        int col = n0 + wc * 64 + n * 16 + li;
        float v = (col < N) ? acc[m][n][reg] : NEGINF;
        if (v > l1) { l2 = l1; l1 = v; nb = n; }
        else if (v > l2) l2 = v;
      }
      const float loc1 = l1;
#pragma unroll
      for (int s = 1; s < 16; s <<= 1) {
        float o1 = __shfl_xor(l1, s, 64);
        float o2 = __shfl_xor(l2, s, 64);
        float hi = fmaxf(l1, o1);
        float lo = fminf(l1, o1);
        l2 = fmaxf(lo, fmaxf(l2, o2));
        l1 = hi;
      }
      unsigned long long bal = __ballot(loc1 == l1);
      unsigned mask16 = (unsigned)(bal >> (lg * 16)) & 0xffffu;
      int first = __builtin_ctz(mask16 | 0x10000u);
      int nbo = __shfl(nb, lg * 16 + first, 64);
      int col1 = n0 + wc * 64 + nbo * 16 + first;
      if (li == 0) {
        int rloc = wr * 64 + m * 16 + lg * 4 + reg;  // row in 256
        stop[(wc * 256 + rloc) * 2 + 0] =
            ((u64)fkey(l1) << 32) | (u32)(~(u32)col1);
        stop[(wc * 256 + rloc) * 2 + 1] = ((u64)fkey(l2) << 32);
      }
    }
  __syncthreads();
  if (t < 256) {
    u64 g1 = 0, g2 = 0;
#pragma unroll
    for (int q = 0; q < 2; ++q) {
      u64 a1 = stop[(q * 256 + t) * 2 + 0], a2 = stop[(q * 256 + t) * 2 + 1];
      u64 n1 = g1 > a1 ? g1 : a1;
      u64 lo = g1 > a1 ? a1 : g1;
      u64 mx = g2 > a2 ? g2 : a2;
      g2 = lo > mx ? lo : mx;
      g1 = n1;
    }
    u64* dst = gtop + ((size_t)(m0 + t) * NTIL + nt) * 2;
    dst[0] = g1;
    dst[1] = g2;
  }
}

// ---------------- K2: merge 24 tiles -> r, worklist + chunk bitmap ----------
__global__ __launch_bounds__(256) void k_reduce(const u64* __restrict__ gtop,
                                                int* __restrict__ r,
                                                int* __restrict__ amb,
                                                u64* __restrict__ rbest,
                                                u32* __restrict__ wl,
                                                u32* __restrict__ cnts,
                                                u64* __restrict__ chunkmap) {
  int row = blockIdx.x * 256 + threadIdx.x;
  if (row >= M) return;
  const u64* src = gtop + (size_t)row * NTIL * 2;
  u64 tops[NTIL];
  u64 g1 = 0, g2 = 0;
#pragma unroll
  for (int tt = 0; tt < NTIL; ++tt) {
    u64 a1 = src[tt * 2], a2 = src[tt * 2 + 1];
    tops[tt] = a1;
    u64 n1 = g1 > a1 ? g1 : a1;
    u64 lo = g1 > a1 ? a1 : g1;
    u64 mx = g2 > a2 ? g2 : a2;
    g2 = lo > mx ? lo : mx;
    g1 = n1;
  }
  int jbest = (int)(~(u32)(g1 & 0xffffffffull));
  r[row] = jbest;
  atomicOr(&chunkmap[jbest], 1ull << (row >> 10));
  float v1 = keyf((u32)(g1 >> 32)), v2 = keyf((u32)(g2 >> 32));
  if (v1 - v2 < GAPTHR) {
    u32 idx = atomicAdd(&cnts[0], 1u);
    if (idx < MAXAMB) {
      amb[idx] = row;
      rbest[row] = 0ull;
      float thr = v1 - GAPTHR;
#pragma unroll
      for (int tt = 0; tt < NTIL; ++tt) {
        if (keyf((u32)(tops[tt] >> 32)) >= thr) {
          u32 wi = atomicAdd(&cnts[1], 1u);
          if (wi < MAXWL) wl[wi] = ((u32)row << 5) | (u32)tt;
        }
      }
    }
  }
}

// ---------------- K3: exact fp32 re-argmax over compact worklist ------------
__global__ __launch_bounds__(256) void k_refine(const float* __restrict__ X,
                                                const float* __restrict__ MU,
                                                const u32* __restrict__ wl,
                                                const u32* __restrict__ cnts,
                                                u64* __restrict__ rbest) {
  __shared__ float xrow[768];
  __shared__ u64 wb[4];
  const int t = threadIdx.x, w = t >> 6, ln = t & 63;
  const int nw = (int)min(cnts[1], (u32)MAXWL);
  for (int u = blockIdx.x; u < nw; u += gridDim.x) {
    const u32 e = wl[u];
    const int row = (int)(e >> 5), tile = (int)(e & 31);

    xrow[t] = X[(size_t)row * K + t];
    xrow[t + 256] = X[(size_t)row * K + t + 256];
    xrow[t + 512] = X[(size_t)row * K + t + 512];
    __syncthreads();

    u64 best = 0;
    for (int q = 0; q < 8; ++q) {
      const int cbase = tile * 128 + w * 32 + q * 4;
      const float* m0p = MU + (size_t)min(cbase + 0, N - 1) * K;
      const float* m1p = MU + (size_t)min(cbase + 1, N - 1) * K;
      const float* m2p = MU + (size_t)min(cbase + 2, N - 1) * K;
      const float* m3p = MU + (size_t)min(cbase + 3, N - 1) * K;
      float p0 = 0.f, p1 = 0.f, p2 = 0.f, p3 = 0.f;
#pragma unroll
      for (int it = 0; it < 3; ++it) {
        int d4 = (ln + it * 64) * 4;
        float4 xv = *reinterpret_cast<const float4*>(&xrow[d4]);
        float4 a0 = *reinterpret_cast<const float4*>(m0p + d4);
        float4 a1 = *reinterpret_cast<const float4*>(m1p + d4);
        float4 a2 = *reinterpret_cast<const float4*>(m2p + d4);
        float4 a3 = *reinterpret_cast<const float4*>(m3p + d4);
        p0 += xv.x * a0.x + xv.y * a0.y + xv.z * a0.z + xv.w * a0.w;
        p1 += xv.x * a1.x + xv.y * a1.y + xv.z * a1.z + xv.w * a1.w;
        p2 += xv.x * a2.x + xv.y * a2.y + xv.z * a2.z + xv.w * a2.w;
        p3 += xv.x * a3.x + xv.y * a3.y + xv.z * a3.z + xv.w * a3.w;
      }
#pragma unroll
      for (int s = 32; s; s >>= 1) {
        p0 += __shfl_xor(p0, s, 64);
        p1 += __shfl_xor(p1, s, 64);
        p2 += __shfl_xor(p2, s, 64);
        p3 += __shfl_xor(p3, s, 64);
      }
      if (ln == 0) {
        float ps[4] = {p0, p1, p2, p3};
#pragma unroll
        for (int i = 0; i < 4; ++i) {
          int c = cbase + i;
          if (c < N) {
            u64 pk = ((u64)fkey(ps[i]) << 32) | (u32)(~(u32)c);
            if (pk > best) best = pk;
          }
        }
      }
    }
    if (ln == 0) wb[w] = best;
    __syncthreads();
    if (t == 0) {
      u64 b = wb[0];
#pragma unroll
      for (int i = 1; i < 4; ++i)
        if (wb[i] > b) b = wb[i];
      atomicMax(&rbest[row], b);
    }
    __syncthreads();
  }
}

// ---------------- K3b: decode refined assignments (+bitmap update) ----------
__global__ __launch_bounds__(256) void k_decode2(const int* __restrict__ amb,
                                                 const u64* __restrict__ rbest,
                                                 const u32* __restrict__ cnts,
                                                 int* __restrict__ r,
                                                 u64* __restrict__ chunkmap) {
  int i = blockIdx.x * 256 + threadIdx.x;
  int n_amb = (int)min(cnts[0], (u32)MAXAMB);
  if (i < n_amb) {
    int row = amb[i];
    int jn = (int)(~(u32)(rbest[row] & 0xffffffffull));
    r[row] = jn;
    atomicOr(&chunkmap[jn], 1ull << (row >> 10));
  }
}

// ---------------- K4: finalize (chunk-bitmap skip + ILP member sum) ---------
__global__ __launch_bounds__(256) void k_finalize(const float* __restrict__ X,
                                                  const float* __restrict__ MU,
                                                  const int* __restrict__ r,
                                                  const u64* __restrict__ chunkmap,
                                                  float* __restrict__ out,
                                                  float* __restrict__ dis_slot) {
#pragma clang fp contract(off)
  const int j = blockIdx.x;
  const int t = threadIdx.x;
  const int lane = t & 63;
  const int wid = t >> 6;
  __shared__ int list[MAXL];
  __shared__ int wc4[4][4];   // [wave][group]
  __shared__ float red[4];
  __shared__ unsigned hist[256];
  __shared__ int selI;

  const u64 cmap = chunkmap[j];
  int cnt = 0;
  for (int ch = 0; ch < 64; ++ch) {
    if (!((cmap >> ch) & 1ull)) continue;  // block-uniform skip
    const int base = ch << 10;
    bool f[4];
    u64 bm[4];
#pragma unroll
    for (int q = 0; q < 4; ++q) {
      f[q] = (r[base + q * 256 + t] == j);
      bm[q] = __ballot(f[q]);
    }
    if (lane == 0) {
#pragma unroll
      for (int q = 0; q < 4; ++q) wc4[wid][q] = __popcll(bm[q]);
    }
    __syncthreads();
    int goff = cnt;
#pragma unroll
    for (int q = 0; q < 4; ++q) {
      if (f[q]) {
        int off = goff;
        for (int ww = 0; ww < wid; ++ww) off += wc4[ww][q];
        int pos = off + __popcll(bm[q] & ((1ull << lane) - 1ull));
        if (pos < MAXL) list[pos] = base + q * 256 + t;
      }
      goff += wc4[0][q] + wc4[1][q] + wc4[2][q] + wc4[3][q];
    }
    cnt = goff;
    __syncthreads();
  }
  int cl = cnt < MAXL ? cnt : MAXL;

  // member sums: 4 independent accumulator chains (ILP), fixed-order combine
  float a0 = 0.f, a1 = 0.f, a2 = 0.f, a3 = 0.f;
  float b0 = 0.f, b1 = 0.f, b2 = 0.f, b3 = 0.f;
  float c0 = 0.f, c1 = 0.f, c2 = 0.f, c3 = 0.f;
  int m = 0;
  for (; m + 3 < cl; m += 4) {
    const float* x0 = X + (size_t)list[m + 0] * K;
    const float* x1 = X + (size_t)list[m + 1] * K;
    const float* x2 = X + (size_t)list[m + 2] * K;
    const float* x3 = X + (size_t)list[m + 3] * K;
    a0 += x0[t]; b0 += x0[t + 256]; c0 += x0[t + 512];
    a1 += x1[t]; b1 += x1[t + 256]; c1 += x1[t + 512];
    a2 += x2[t]; b2 += x2[t + 256]; c2 += x2[t + 512];
    a3 += x3[t]; b3 += x3[t + 256]; c3 += x3[t + 512];
  }
  for (; m < cl; ++m) {
    const float* xr = X + (size_t)list[m] * K;
    a0 += xr[t]; b0 += xr[t + 256]; c0 += xr[t + 512];
  }
  float s0 = ((a0 + a1) + a2) + a3;
  float s1 = ((b0 + b1) + b2) + b3;
  float s2 = ((c0 + c1) + c2) + c3;

  const float mu0 = MU[(size_t)j * K + t];
  const float mu1 = MU[(size_t)j * K + t + 256];
  const float mu2 = MU[(size_t)j * K + t + 512];

  float u0, u1, u2;
  if (cnt >= 1) {
    float c = (float)cnt;
    u0 = s0 / c; u1 = s1 / c; u2 = s2 / c;
  } else {
    u0 = mu0; u1 = mu1; u2 = mu2;
  }
  float v0 = u0 * 0.2f + mu0 * 0.8f;
  float v1 = u1 * 0.2f + mu1 * 0.8f;
  float v2 = u2 * 0.2f + mu2 * 0.8f;

  float ss = v0 * v0 + v1 * v1 + v2 * v2;
#pragma unroll
  for (int s = 32; s > 0; s >>= 1) ss += __shfl_down(ss, s, 64);
  if (lane == 0) red[wid] = ss;
  __syncthreads();
  float tot = red[0] + red[1] + red[2] + red[3];
  float den = sqrtf(tot);
  den = fmaxf(den, 1e-12f);
  float un0 = v0 / den, un1 = v1 / den, un2 = v2 / den;
  unsigned k0b = __float_as_uint(fabsf(un0));
  unsigned k1b = __float_as_uint(fabsf(un1));
  unsigned k2b = __float_as_uint(fabsf(un2));
  __syncthreads();

  unsigned cur = 0;
  int need = KSP;
  for (int sh = 24; sh >= 0; sh -= 8) {
    hist[t] = 0u;
    if (t == 0) selI = -1;
    __syncthreads();
    bool m0_ = (sh == 24) || ((k0b >> (sh + 8)) == (cur >> (sh + 8)));
    bool m1_ = (sh == 24) || ((k1b >> (sh + 8)) == (cur >> (sh + 8)));
    bool m2_ = (sh == 24) || ((k2b >> (sh + 8)) == (cur >> (sh + 8)));
    if (m0_) atomicAdd(&hist[(k0b >> sh) & 255u], 1u);
    if (m1_) atomicAdd(&hist[(k1b >> sh) & 255u], 1u);
    if (m2_) atomicAdd(&hist[(k2b >> sh) & 255u], 1u);
    __syncthreads();
#pragma unroll
    for (int off = 1; off < 256; off <<= 1) {
      unsigned nb = (t + off < 256) ? hist[t + off] : 0u;
      __syncthreads();
      hist[t] += nb;
      __syncthreads();
    }
    if (hist[t] >= (unsigned)need) atomicMax(&selI, t);
    __syncthreads();
    int b = selI < 0 ? 0 : selI;
    unsigned above = (b < 255) ? hist[b + 1] : 0u;
    cur |= ((unsigned)b << sh);
    need = need - (int)above;
    __syncthreads();
  }
  unsigned th = cur;

  float o0 = (k0b >= th) ? un0 : 0.0f;
  float o1 = (k1b >= th) ? un1 : 0.0f;
  float o2 = (k2b >= th) ? un2 : 0.0f;
  out[(size_t)j * K + t] = o0;
  out[(size_t)j * K + t + 256] = o1;
  out[(size_t)j * K + t + 512] = o2;

  float q0 = o0 - mu0, q1 = o1 - mu1, q2 = o2 - mu2;
  float dq = q0 * q0 + q1 * q1 + q2 * q2;
#pragma unroll
  for (int s = 32; s > 0; s >>= 1) dq += __shfl_down(dq, s, 64);
  __syncthreads();
  if (lane == 0) red[wid] = dq;
  __syncthreads();
  if (t == 0) {
    float dtot = red[0] + red[1] + red[2] + red[3];
    float dn = sqrtf(dtot);
    atomicMax((unsigned*)dis_slot, __float_as_uint(dn));
  }
}

// ================= fallback fp32 path (ws too small) =================
__global__ __launch_bounds__(256) void k0_init(u64* __restrict__ best,
                                               float* __restrict__ dis_slot) {
  int i = blockIdx.x * 256 + threadIdx.x;
  if (i < M) best[i] = 0ull;
  if (i == 0) *dis_slot = 0.0f;
}

__global__ __launch_bounds__(256) void k1_f32(const float* __restrict__ X,
                                              const float* __restrict__ MU,
                                              u64* __restrict__ best) {
  __shared__ float Asf[16][64];
  __shared__ float Bsf[16][64];
  const int m0 = blockIdx.x * 64;
  const int n0 = blockIdx.y * 64;
  const int t = threadIdx.x;
  const int tx = t & 15, ty = t >> 4;
  const int lrow = t >> 2, lcg = t & 3;

  float acc[4][4];
#pragma unroll
  for (int i = 0; i < 4; ++i)
#pragma unroll
    for (int jj = 0; jj < 4; ++jj) acc[i][jj] = 0.0f;

  const float* aptr = X + (size_t)(m0 + lrow) * K + lcg * 4;
  const bool bvalid = (n0 + lrow) < N;
  const float* bptr = MU + (size_t)(bvalid ? (n0 + lrow) : 0) * K + lcg * 4;

  for (int k0 = 0; k0 < K; k0 += 16) {
    float4 av = *reinterpret_cast<const float4*>(aptr + k0);
    float4 bv = make_float4(0.f, 0.f, 0.f, 0.f);
    if (bvalid) bv = *reinterpret_cast<const float4*>(bptr + k0);
    Asf[lcg * 4 + 0][lrow] = av.x; Asf[lcg * 4 + 1][lrow] = av.y;
    Asf[lcg * 4 + 2][lrow] = av.z; Asf[lcg * 4 + 3][lrow] = av.w;
    Bsf[lcg * 4 + 0][lrow] = bv.x; Bsf[lcg * 4 + 1][lrow] = bv.y;
    Bsf[lcg * 4 + 2][lrow] = bv.z; Bsf[lcg * 4 + 3][lrow] = bv.w;
    __syncthreads();
#pragma unroll
    for (int kk = 0; kk < 16; ++kk) {
      float4 af = *reinterpret_cast<const float4*>(&Asf[kk][ty * 4]);
      float4 bf = *reinterpret_cast<const float4*>(&Bsf[kk][tx * 4]);
      float a[4] = {af.x, af.y, af.z, af.w};
      float b[4] = {bf.x, bf.y, bf.z, bf.w};
#pragma unroll
      for (int i = 0; i < 4; ++i)
#pragma unroll
        for (int jj = 0; jj < 4; ++jj)
          acc[i][jj] = fmaf(a[i], b[jj], acc[i][jj]);
    }
    __syncthreads();
  }
#pragma unroll
  for (int i = 0; i < 4; ++i) {
    u64 bk = 0ull;
#pragma unroll
    for (int jj = 0; jj < 4; ++jj) {
      int col = n0 + tx * 4 + jj;
      if (col < N) {
        u64 pk = ((u64)fkey(acc[i][jj]) << 32) | (u32)(~(u32)col);
        if (pk > bk) bk = pk;
      }
    }
#pragma unroll
    for (int s = 1; s < 16; s <<= 1) {
      u64 o = __shfl_xor((unsigned long long)bk, s, 64);
      if (o > bk) bk = o;
    }
    if (tx == 0) atomicMax(&best[m0 + ty * 4 + i], bk);
  }
}

__global__ __launch_bounds__(256) void k2_decode(const u64* __restrict__ best,
                                                 int* __restrict__ r) {
  int i = blockIdx.x * 256 + threadIdx.x;
  if (i < M) r[i] = (int)(~(u32)(best[i] & 0xffffffffull));
}

__global__ __launch_bounds__(256) void k_mapall(u64* __restrict__ chunkmap) {
  int i = blockIdx.x * 256 + threadIdx.x;
  if (i < N) chunkmap[i] = ~0ull;
}

extern "C" void kernel_launch(void* const* d_in, const int* in_sizes, int n_in,
                              void* d_out, int out_size, void* d_ws, size_t ws_size,
                              hipStream_t stream) {
  const float* X = (const float*)d_in[0];
  const float* MU = (const float*)d_in[1];
  float* out = (float*)d_out;
  float* dis_slot = out + (size_t)N * K;

  if (ws_size >= WS_NEED) {
    unsigned short* A2 = (unsigned short*)((char*)d_ws + OFF_A2);
    unsigned short* B2 = (unsigned short*)((char*)d_ws + OFF_B2);
    u64* gtop = (u64*)((char*)d_ws + OFF_GTOP);
    u64* rbest = (u64*)((char*)d_ws + OFF_RB);
    int* r = (int*)((char*)d_ws + OFF_R);
    int* amb = (int*)((char*)d_ws + OFF_AMB);
    u32* wl = (u32*)((char*)d_ws + OFF_WL);
    u32* cnts = (u32*)((char*)d_ws + OFF_CNT);
    u64* chunkmap = (u64*)((char*)d_ws + OFF_CM);

    k_convx<<<8192, 256, 0, stream>>>(X, A2);
    k_convmu<<<NPAD, 256, 0, stream>>>(MU, B2, cnts, chunkmap, dis_slot);
    k_gemm<<<256 * NTIL, 512, 0, stream>>>(A2, B2, gtop);
    k_reduce<<<M / 256, 256, 0, stream>>>(gtop, r, amb, rbest, wl, cnts, chunkmap);
    k_refine<<<2048, 256, 0, stream>>>(X, MU, wl, cnts, rbest);
    k_decode2<<<MAXAMB / 256, 256, 0, stream>>>(amb, rbest, cnts, r, chunkmap);
    k_finalize<<<N, 256, 0, stream>>>(X, MU, r, chunkmap, out, dis_slot);
  } else {
    u64* best = (u64*)d_ws;
    int* r = (int*)((char*)d_ws + (size_t)M * sizeof(u64));
    u64* chunkmap = (u64*)((char*)d_ws + (size_t)M * 12);
    k0_init<<<M / 256, 256, 0, stream>>>(best, dis_slot);
    k_mapall<<<(N + 255) / 256, 256, 0, stream>>>(chunkmap);
    dim3 g1(M / 64, (N + 63) / 64);
    k1_f32<<<g1, 256, 0, stream>>>(X, MU, best);
    k2_decode<<<M / 256, 256, 0, stream>>>(best, r);
    k_finalize<<<N, 256, 0, stream>>>(X, MU, r, chunkmap, out, dis_slot);
  }
}